// Round 1
// baseline (1645.684 us; speedup 1.0000x reference)
//
#include <hip/hip_runtime.h>
#include <math.h>

#define B_   8
#define LQ_  1024
#define D_   256
#define NH_  8
#define DH_  32
#define LIN_ 13125

__device__ __forceinline__ float4 f4add(float4 a, float4 b){
  return make_float4(a.x+b.x, a.y+b.y, a.z+b.z, a.w+b.w);
}
__device__ __forceinline__ float wredsum(float v){
  #pragma unroll
  for (int o=1;o<64;o<<=1) v += __shfl_xor(v,o,64);
  return v;
}
__device__ __forceinline__ float wredmax(float v){
  #pragma unroll
  for (int o=1;o<64;o<<=1) v = fmaxf(v,__shfl_xor(v,o,64));
  return v;
}

// ---------------- elementwise prep ----------------
__global__ __launch_bounds__(256) void k_prep(
    const float4* __restrict__ qe, const float4* __restrict__ rf,
    const float4* __restrict__ qo, const float4* __restrict__ rp,
    float4* __restrict__ src, float4* __restrict__ q)
{
  int i = blockIdx.x*256 + threadIdx.x;
  float4 s = f4add(qe[i], rf[i]);
  src[i] = s;
  q[i] = f4add(s, f4add(qo[i], rp[i]));
}

__global__ __launch_bounds__(256) void k_dq(
    const float4* __restrict__ tgt, const float4* __restrict__ qo,
    const float4* __restrict__ rp, const float4* __restrict__ rf,
    float4* __restrict__ dq)
{
  int i = blockIdx.x*256 + threadIdx.x;
  dq[i] = f4add(f4add(tgt[i], qo[i]), f4add(rp[i], rf[i]));
}

// ---------------- generic fp32 GEMM: C = A @ W + bias (opt relu) ----------------
// A: MxK row-major (lda), W: KxN row-major (ldw), C: MxN row-major (ldc)
__global__ __launch_bounds__(256) void k_gemm(
    const float* __restrict__ A, int lda,
    const float* __restrict__ Wt, int ldw,
    const float* __restrict__ bias,
    float* __restrict__ C, int ldc,
    int M, int N, int K, int relu)
{
  __shared__ float As[16][68];
  __shared__ float Bs[16][68];
  const int t  = threadIdx.x;
  const int tx = t & 15, ty = t >> 4;
  const int m0 = blockIdx.y * 64;
  const int n0 = blockIdx.x * 64;
  const int la_m = t >> 2;
  const int la_k = (t & 3) << 2;
  const int lb_k = t >> 4;
  const int lb_n = (t & 15) << 2;
  float acc[4][4] = {};
  for (int kb = 0; kb < K; kb += 16) {
    float4 av = make_float4(0.f,0.f,0.f,0.f);
    const int am = m0 + la_m;
    if (am < M)
      av = *reinterpret_cast<const float4*>(A + (size_t)am*lda + kb + la_k);
    As[la_k+0][la_m]=av.x; As[la_k+1][la_m]=av.y;
    As[la_k+2][la_m]=av.z; As[la_k+3][la_m]=av.w;
    float4 bv = make_float4(0.f,0.f,0.f,0.f);
    {
      const float* wr = Wt + (size_t)(kb + lb_k)*ldw;
      const int bn = n0 + lb_n;
      if (bn + 3 < N) {
        bv = *reinterpret_cast<const float4*>(wr + bn);
      } else {
        if (bn+0 < N) bv.x = wr[bn+0];
        if (bn+1 < N) bv.y = wr[bn+1];
        if (bn+2 < N) bv.z = wr[bn+2];
      }
    }
    *reinterpret_cast<float4*>(&Bs[lb_k][lb_n]) = bv;
    __syncthreads();
    #pragma unroll
    for (int k = 0; k < 16; ++k) {
      float4 a4 = *reinterpret_cast<const float4*>(&As[k][ty<<2]);
      float4 b4 = *reinterpret_cast<const float4*>(&Bs[k][tx<<2]);
      float aa[4] = {a4.x,a4.y,a4.z,a4.w};
      float bb[4] = {b4.x,b4.y,b4.z,b4.w};
      #pragma unroll
      for (int i=0;i<4;++i)
        #pragma unroll
        for (int j=0;j<4;++j)
          acc[i][j] = fmaf(aa[i], bb[j], acc[i][j]);
    }
    __syncthreads();
  }
  #pragma unroll
  for (int i=0;i<4;++i){
    const int row = m0 + (ty<<2) + i;
    if (row >= M) continue;
    #pragma unroll
    for (int j=0;j<4;++j){
      const int col = n0 + (tx<<2) + j;
      if (col >= N) continue;
      float v = acc[i][j] + bias[col];
      if (relu) v = fmaxf(v, 0.f);
      C[(size_t)row*ldc + col] = v;
    }
  }
}

// ---------------- flash-style MHA ----------------
// QK: (B*LQ,512) qp cols 0..255, kp cols 256..511 ; VP: (B*LQ,256) ; O: (B*LQ,256)
__global__ __launch_bounds__(256) void k_attn(
    const float* __restrict__ QK,
    const float* __restrict__ VP,
    const unsigned char* __restrict__ mask,
    float* __restrict__ O)
{
  const int qt = blockIdx.x, h = blockIdx.y, b = blockIdx.z;
  const int t = threadIdx.x;
  const int wave = t >> 6, lane = t & 63;
  const int half = lane >> 5, dd = lane & 31;
  __shared__ float Ks[64][33];
  __shared__ float Vs[64][33];
  __shared__ float Qs[16][33];
  __shared__ float Ps[16][64];
  const int q0 = qt << 4;
  for (int i = t; i < 512; i += 256) {
    int r = i >> 5, d = i & 31;
    Qs[r][d] = QK[(size_t)(b*LQ_ + q0 + r)*512 + h*32 + d];
  }
  float m_[4], l_[4], o_[4];
  #pragma unroll
  for (int r=0;r<4;++r){ m_[r] = -INFINITY; l_[r]=0.f; o_[r]=0.f; }
  const int r0 = wave << 2;
  for (int kt = 0; kt < 16; ++kt) {
    __syncthreads();
    const int k0 = kt << 6;
    for (int i = t; i < 2048; i += 256) {
      int kk = i >> 5, d = i & 31;
      size_t rowg = (size_t)(b*LQ_ + k0 + kk);
      Ks[kk][d] = QK[rowg*512 + 256 + h*32 + d];
      Vs[kk][d] = VP[rowg*256 + h*32 + d];
    }
    __syncthreads();
    const float mb = mask[b*LQ_ + k0 + lane] ? -1e9f : 0.f;
    #pragma unroll
    for (int r=0;r<4;++r){
      const int qr = r0 + r;
      float s = 0.f;
      #pragma unroll
      for (int d=0; d<32; ++d) s = fmaf(Qs[qr][d], Ks[lane][d], s);
      s = s*0.17677669529663687f + mb;
      float tm = wredmax(s);
      float mnew = fmaxf(m_[r], tm);
      float p = __expf(s - mnew);
      float ts = wredsum(p);
      float scale = __expf(m_[r] - mnew);
      m_[r] = mnew;
      l_[r] = l_[r]*scale + ts;
      Ps[qr][lane] = p;
      float a = o_[r]*scale;
      #pragma unroll
      for (int jj=0;jj<32;++jj){
        int j = (half<<5) + jj;
        a = fmaf(Ps[qr][j], Vs[j][dd], a);
      }
      o_[r] = a;
    }
  }
  #pragma unroll
  for (int r=0;r<4;++r){
    float v = o_[r] + __shfl_down(o_[r], 32, 64);
    if (lane < 32)
      O[(size_t)(b*LQ_ + q0 + r0 + r)*256 + h*32 + lane] = v / l_[r];
  }
}

// ---------------- fused residual-add + LayerNorm (rows of 256) ----------------
__global__ __launch_bounds__(256) void k_addln(
    const float* __restrict__ X, const float* __restrict__ Y,
    const float* __restrict__ g, const float* __restrict__ be,
    float* __restrict__ out)
{
  const int wave = threadIdx.x >> 6, lane = threadIdx.x & 63;
  const int row = blockIdx.x*4 + wave;
  const float4 x = reinterpret_cast<const float4*>(X + (size_t)row*256)[lane];
  const float4 y = reinterpret_cast<const float4*>(Y + (size_t)row*256)[lane];
  float4 v = f4add(x,y);
  float s = wredsum(v.x+v.y+v.z+v.w);
  const float mean = s * 0.00390625f;
  float4 d = make_float4(v.x-mean, v.y-mean, v.z-mean, v.w-mean);
  float sq = wredsum(d.x*d.x + d.y*d.y + d.z*d.z + d.w*d.w);
  const float rstd = rsqrtf(sq*0.00390625f + 1e-5f);
  const float4 gg = reinterpret_cast<const float4*>(g)[lane];
  const float4 bb = reinterpret_cast<const float4*>(be)[lane];
  float4 o = make_float4(d.x*rstd*gg.x + bb.x, d.y*rstd*gg.y + bb.y,
                         d.z*rstd*gg.z + bb.z, d.w*rstd*gg.w + bb.w);
  reinterpret_cast<float4*>(out + (size_t)row*256)[lane] = o;
}

// ---------------- deform: per-(b,q,h) softmax + bilinear weights ----------------
__global__ __launch_bounds__(256) void k_dwt(
    const float* __restrict__ offb,   // (B*LQ,192)
    const float* __restrict__ attb,   // (B*LQ,96)
    const float* __restrict__ refp,   // (B*LQ,2)
    float* __restrict__ wbuf)         // (B*LQ*NH) * 12 points * (4 idx + 4 w)
{
  const int idx = blockIdx.x*256 + threadIdx.x;
  if (idx >= B_*LQ_*NH_) return;
  const int h = idx & 7, bq = idx >> 3;
  const float* al = attb + (size_t)bq*96 + h*12;
  float lg[12];
  float mx = -INFINITY;
  #pragma unroll
  for (int i=0;i<12;++i){ lg[i] = al[i]; mx = fmaxf(mx, lg[i]); }
  float se = 0.f;
  #pragma unroll
  for (int i=0;i<12;++i){ lg[i] = __expf(lg[i]-mx); se += lg[i]; }
  const float inv = 1.f/se;
  const float rx = refp[(size_t)bq*2+0], ry = refp[(size_t)bq*2+1];
  const float* ofs = offb + (size_t)bq*192 + h*24;
  float* wout = wbuf + (size_t)idx*96;
  int* iout = reinterpret_cast<int*>(wout);
  const int HH[3]={100,50,25}, WW[3]={100,50,25}, SS[3]={0,10000,12500};
  const int vb = (bq >> 10) * LIN_;
  #pragma unroll
  for (int l=0;l<3;++l){
    const float Wf = (float)WW[l], Hf = (float)HH[l];
    const int Wi = WW[l], Hi = HH[l], s0 = SS[l];
    #pragma unroll
    for (int p=0;p<4;++p){
      const int pt = l*4+p;
      const float ox = ofs[pt*2+0], oy = ofs[pt*2+1];
      const float x = (rx + ox/Wf)*Wf - 0.5f;
      const float y = (ry + oy/Hf)*Hf - 0.5f;
      const float x0f = floorf(x), y0f = floorf(y);
      const float wx = x - x0f, wy = y - y0f;
      const int x0 = (int)x0f, y0 = (int)y0f;
      const float aw = lg[pt]*inv;
      const float w00=(1.f-wy)*(1.f-wx)*aw, w01=(1.f-wy)*wx*aw;
      const float w10=wy*(1.f-wx)*aw,       w11=wy*wx*aw;
      const int xs0 = min(max(x0,0),Wi-1),   xs1 = min(max(x0+1,0),Wi-1);
      const int ys0 = min(max(y0,0),Hi-1),   ys1 = min(max(y0+1,0),Hi-1);
      const bool vx0 = (x0>=0)&&(x0<Wi),     vx1 = (x0+1>=0)&&(x0+1<Wi);
      const bool vy0 = (y0>=0)&&(y0<Hi),     vy1 = (y0+1>=0)&&(y0+1<Hi);
      iout[pt*8+0] = vb + s0 + ys0*Wi + xs0;
      iout[pt*8+1] = vb + s0 + ys0*Wi + xs1;
      iout[pt*8+2] = vb + s0 + ys1*Wi + xs0;
      iout[pt*8+3] = vb + s0 + ys1*Wi + xs1;
      wout[pt*8+4] = (vy0&&vx0)? w00 : 0.f;
      wout[pt*8+5] = (vy0&&vx1)? w01 : 0.f;
      wout[pt*8+6] = (vy1&&vx0)? w10 : 0.f;
      wout[pt*8+7] = (vy1&&vx1)? w11 : 0.f;
    }
  }
}

// ---------------- deform: gather & accumulate ----------------
__global__ __launch_bounds__(256) void k_dgather(
    const float* __restrict__ vproj,   // (B*LIN,256)
    const float* __restrict__ wbuf,
    float* __restrict__ out)           // (B*LQ,256)
{
  const int t = blockIdx.x*256 + threadIdx.x;  // (bq*8+h)*32+d
  const int col = t & 255;
  const int gh = t >> 5;
  const float* wp = wbuf + (size_t)gh*96;
  const int* ip = reinterpret_cast<const int*>(wp);
  float acc = 0.f;
  #pragma unroll
  for (int pt=0; pt<12; ++pt){
    const int b0 = pt*8;
    acc = fmaf(wp[b0+4], vproj[(size_t)ip[b0+0]*256 + col], acc);
    acc = fmaf(wp[b0+5], vproj[(size_t)ip[b0+1]*256 + col], acc);
    acc = fmaf(wp[b0+6], vproj[(size_t)ip[b0+2]*256 + col], acc);
    acc = fmaf(wp[b0+7], vproj[(size_t)ip[b0+3]*256 + col], acc);
  }
  out[t] = acc;
}

extern "C" void kernel_launch(void* const* d_in, const int* in_sizes, int n_in,
                              void* d_out, int out_size, void* d_ws, size_t ws_size,
                              hipStream_t stream)
{
  const float* qe      = (const float*)d_in[0];
  const unsigned char* qmask = (const unsigned char*)d_in[1];
  const float* qo      = (const float*)d_in[2];
  const float* values  = (const float*)d_in[3];
  const float* refp    = (const float*)d_in[4];
  const float* rp      = (const float*)d_in[5];
  const float* rf      = (const float*)d_in[6];
  const float* sa_in_w = (const float*)d_in[10];
  const float* sa_in_b = (const float*)d_in[11];
  const float* sa_out_w= (const float*)d_in[12];
  const float* sa_out_b= (const float*)d_in[13];
  const float* sa_ln1_g= (const float*)d_in[14];
  const float* sa_ln1_b= (const float*)d_in[15];
  const float* sa_l1_w = (const float*)d_in[16];
  const float* sa_l1_b = (const float*)d_in[17];
  const float* sa_l2_w = (const float*)d_in[18];
  const float* sa_l2_b = (const float*)d_in[19];
  const float* sa_ln2_g= (const float*)d_in[20];
  const float* sa_ln2_b= (const float*)d_in[21];
  const float* da_val_w= (const float*)d_in[22];
  const float* da_val_b= (const float*)d_in[23];
  const float* da_off_w= (const float*)d_in[24];
  const float* da_off_b= (const float*)d_in[25];
  const float* da_att_w= (const float*)d_in[26];
  const float* da_att_b= (const float*)d_in[27];
  const float* da_out_w= (const float*)d_in[28];
  const float* da_out_b= (const float*)d_in[29];
  const float* ln1_g   = (const float*)d_in[30];
  const float* ln1_b   = (const float*)d_in[31];
  const float* ff1_w   = (const float*)d_in[32];
  const float* ff1_b   = (const float*)d_in[33];
  const float* ff2_w   = (const float*)d_in[34];
  const float* ff2_b   = (const float*)d_in[35];
  const float* ln2_g   = (const float*)d_in[36];
  const float* ln2_b   = (const float*)d_in[37];

  float* Wk = (float*)d_ws;
  const size_t M2 = 2097152;          // B*LQ*D
  float* A  = Wk;                     // src / tgt (persistent)
  float* Bq = Wk + M2;                // q / dq
  float* F  = Wk + 2*M2;              // gemm-out tmp before LN
  float* G  = Wk + 3*M2;              // 8M multi-use region
  float* H  = Wk + 7*M2;              // vproj: 105000*256 = 26,880,000
  float* I  = H + 26880000;           // off logits: 8192*192
  float* J  = I + 1572864;            // att logits: 8192*96
  float* Kw = J + 786432;             // bilinear weights: 65536*96
  float* qk = G;                      // (8192,512)
  float* vp = G + 4*M2;               // (8192,256)
  float* ao = G + 6*M2;               // (8192,256)

  dim3 blk(256);
  // src = qe+rf ; q = src+qo+rp
  k_prep<<<2048, blk, 0, stream>>>((const float4*)qe,(const float4*)rf,
                                   (const float4*)qo,(const float4*)rp,
                                   (float4*)A,(float4*)Bq);
  // qp|kp = q @ in_w[:, :512] ; vp = src @ in_w[:, 512:]
  k_gemm<<<dim3(8,128), blk, 0, stream>>>(Bq,256, sa_in_w,768, sa_in_b, qk,512, 8192,512,256, 0);
  k_gemm<<<dim3(4,128), blk, 0, stream>>>(A,256, sa_in_w+512,768, sa_in_b+512, vp,256, 8192,256,256, 0);
  k_attn<<<dim3(64,8,8), blk, 0, stream>>>(qk, vp, qmask, ao);
  k_gemm<<<dim3(4,128), blk, 0, stream>>>(ao,256, sa_out_w,256, sa_out_b, F,256, 8192,256,256, 0);
  k_addln<<<2048, blk, 0, stream>>>(A, F, sa_ln1_g, sa_ln1_b, A);
  // FFN 1
  k_gemm<<<dim3(16,128), blk, 0, stream>>>(A,256, sa_l1_w,1024, sa_l1_b, G,1024, 8192,1024,256, 1);
  k_gemm<<<dim3(4,128), blk, 0, stream>>>(G,1024, sa_l2_w,256, sa_l2_b, F,256, 8192,256,1024, 0);
  k_addln<<<2048, blk, 0, stream>>>(A, F, sa_ln2_g, sa_ln2_b, A);
  // deformable attention
  k_dq<<<2048, blk, 0, stream>>>((const float4*)A,(const float4*)qo,
                                 (const float4*)rp,(const float4*)rf,(float4*)Bq);
  k_gemm<<<dim3(4,1641), blk, 0, stream>>>(values,256, da_val_w,256, da_val_b, H,256, 105000,256,256, 0);
  k_gemm<<<dim3(3,128), blk, 0, stream>>>(Bq,256, da_off_w,192, da_off_b, I,192, 8192,192,256, 0);
  k_gemm<<<dim3(2,128), blk, 0, stream>>>(Bq,256, da_att_w,96, da_att_b, J,96, 8192,96,256, 0);
  k_dwt<<<256, blk, 0, stream>>>(I, J, refp, Kw);
  k_dgather<<<8192, blk, 0, stream>>>(H, Kw, G);
  k_gemm<<<dim3(4,128), blk, 0, stream>>>(G,256, da_out_w,256, da_out_b, F,256, 8192,256,256, 0);
  k_addln<<<2048, blk, 0, stream>>>(A, F, ln1_g, ln1_b, A);
  // FFN 2
  k_gemm<<<dim3(16,128), blk, 0, stream>>>(A,256, ff1_w,1024, ff1_b, G,1024, 8192,1024,256, 1);
  k_gemm<<<dim3(4,128), blk, 0, stream>>>(G,1024, ff2_w,256, ff2_b, F,256, 8192,256,1024, 0);
  k_addln<<<2048, blk, 0, stream>>>(A, F, ln2_g, ln2_b, (float*)d_out);
}

// Round 2
// 854.090 us; speedup vs baseline: 1.9268x; 1.9268x over previous
//
#include <hip/hip_runtime.h>
#include <math.h>

#define B_   8
#define LQ_  1024
#define D_   256
#define NH_  8
#define DH_  32
#define LIN_ 13125

typedef __attribute__((ext_vector_type(4))) float f32x4;
typedef __attribute__((ext_vector_type(8))) short bf16x8;
typedef __attribute__((ext_vector_type(4))) short bf16x4;

__device__ __forceinline__ float4 f4add(float4 a, float4 b){
  return make_float4(a.x+b.x, a.y+b.y, a.z+b.z, a.w+b.w);
}
__device__ __forceinline__ float wredsum(float v){
  #pragma unroll
  for (int o=1;o<64;o<<=1) v += __shfl_xor(v,o,64);
  return v;
}
__device__ __forceinline__ unsigned short f2bf(float f){
  unsigned u = __float_as_uint(f);
  unsigned r = (u + 0x7fffu + ((u>>16)&1u)) >> 16;
  return (unsigned short)r;
}
__device__ __forceinline__ float fexp2(float x){
#if __has_builtin(__builtin_amdgcn_exp2f)
  return __builtin_amdgcn_exp2f(x);
#else
  return exp2f(x);
#endif
}
__device__ __forceinline__ f32x4 mfma16x16(bf16x4 a, bf16x4 b, f32x4 c){
#if __has_builtin(__builtin_amdgcn_mfma_f32_16x16x16_bf16)
  return __builtin_amdgcn_mfma_f32_16x16x16_bf16(a, b, c, 0, 0, 0);
#elif __has_builtin(__builtin_amdgcn_mfma_f32_16x16x16bf16_1k)
  return __builtin_amdgcn_mfma_f32_16x16x16bf16_1k(a, b, c, 0, 0, 0);
#else
  asm volatile("s_nop 1\n\tv_mfma_f32_16x16x16_bf16 %0, %1, %2, %0"
               : "+v"(c) : "v"(a), "v"(b));
  return c;
#endif
}

// ---------------- elementwise prep ----------------
__global__ __launch_bounds__(256) void k_prep(
    const float4* __restrict__ qe, const float4* __restrict__ rf,
    const float4* __restrict__ qo, const float4* __restrict__ rp,
    float4* __restrict__ src, float4* __restrict__ q)
{
  int i = blockIdx.x*256 + threadIdx.x;
  float4 s = f4add(qe[i], rf[i]);
  src[i] = s;
  q[i] = f4add(s, f4add(qo[i], rp[i]));
}

__global__ __launch_bounds__(256) void k_dq(
    const float4* __restrict__ tgt, const float4* __restrict__ qo,
    const float4* __restrict__ rp, const float4* __restrict__ rf,
    float4* __restrict__ dq)
{
  int i = blockIdx.x*256 + threadIdx.x;
  dq[i] = f4add(f4add(tgt[i], qo[i]), f4add(rp[i], rf[i]));
}

// ---------------- generic fp32 GEMM: C = A @ W + bias (opt relu) ----------------
__global__ __launch_bounds__(256) void k_gemm(
    const float* __restrict__ A, int lda,
    const float* __restrict__ Wt, int ldw,
    const float* __restrict__ bias,
    float* __restrict__ C, int ldc,
    int M, int N, int K, int relu)
{
  __shared__ float As[16][68];
  __shared__ float Bs[16][68];
  const int t  = threadIdx.x;
  const int tx = t & 15, ty = t >> 4;
  const int m0 = blockIdx.y * 64;
  const int n0 = blockIdx.x * 64;
  const int la_m = t >> 2;
  const int la_k = (t & 3) << 2;
  const int lb_k = t >> 4;
  const int lb_n = (t & 15) << 2;
  float acc[4][4] = {};
  for (int kb = 0; kb < K; kb += 16) {
    float4 av = make_float4(0.f,0.f,0.f,0.f);
    const int am = m0 + la_m;
    if (am < M)
      av = *reinterpret_cast<const float4*>(A + (size_t)am*lda + kb + la_k);
    As[la_k+0][la_m]=av.x; As[la_k+1][la_m]=av.y;
    As[la_k+2][la_m]=av.z; As[la_k+3][la_m]=av.w;
    float4 bv = make_float4(0.f,0.f,0.f,0.f);
    {
      const float* wr = Wt + (size_t)(kb + lb_k)*ldw;
      const int bn = n0 + lb_n;
      if (bn + 3 < N) {
        bv = *reinterpret_cast<const float4*>(wr + bn);
      } else {
        if (bn+0 < N) bv.x = wr[bn+0];
        if (bn+1 < N) bv.y = wr[bn+1];
        if (bn+2 < N) bv.z = wr[bn+2];
      }
    }
    *reinterpret_cast<float4*>(&Bs[lb_k][lb_n]) = bv;
    __syncthreads();
    #pragma unroll
    for (int k = 0; k < 16; ++k) {
      float4 a4 = *reinterpret_cast<const float4*>(&As[k][ty<<2]);
      float4 b4 = *reinterpret_cast<const float4*>(&Bs[k][tx<<2]);
      float aa[4] = {a4.x,a4.y,a4.z,a4.w};
      float bb[4] = {b4.x,b4.y,b4.z,b4.w};
      #pragma unroll
      for (int i=0;i<4;++i)
        #pragma unroll
        for (int j=0;j<4;++j)
          acc[i][j] = fmaf(aa[i], bb[j], acc[i][j]);
    }
    __syncthreads();
  }
  #pragma unroll
  for (int i=0;i<4;++i){
    const int row = m0 + (ty<<2) + i;
    if (row >= M) continue;
    #pragma unroll
    for (int j=0;j<4;++j){
      const int col = n0 + (tx<<2) + j;
      if (col >= N) continue;
      float v = acc[i][j] + bias[col];
      if (relu) v = fmaxf(v, 0.f);
      C[(size_t)row*ldc + col] = v;
    }
  }
}

// ---------------- convert K -> bf16 [bh][1024][32]; V -> bf16 transposed [bh][32][1024] ----------------
__global__ __launch_bounds__(256) void k_cvt(
    const float* __restrict__ QKsrc,   // (8192,512), K in cols 256..511
    const float* __restrict__ VP,      // (8192,256)
    unsigned short* __restrict__ Kbf,
    unsigned short* __restrict__ Vtb)
{
  __shared__ unsigned short vt[256][65];
  const int r0 = blockIdx.x * 64;
  const int b  = r0 >> 10;
  const int rl0 = r0 & 1023;
  const int t = threadIdx.x;
  for (int idx = t; idx < 64*256; idx += 256) {
    int r = idx >> 8, c = idx & 255;
    float v = QKsrc[(size_t)(r0 + r)*512 + 256 + c];
    int h = c >> 5, d = c & 31;
    Kbf[(size_t)(b*8 + h)*32768 + (size_t)(rl0 + r)*32 + d] = f2bf(v);
  }
  for (int idx = t; idx < 64*256; idx += 256) {
    int r = idx >> 8, c = idx & 255;
    vt[c][r] = f2bf(VP[(size_t)(r0 + r)*256 + c]);
  }
  __syncthreads();
  for (int idx = t; idx < 64*256; idx += 256) {
    int dall = idx >> 6, r = idx & 63;
    Vtb[(size_t)(b*8 + (dall>>5))*32768 + (size_t)(dall & 31)*1024 + rl0 + r] = vt[dall][r];
  }
}

// ---------------- MFMA flash attention ----------------
// S^T tile = mfma_16x16x32(K_frag, Q_frag): lane holds S^T[k0+4*lg+i][q0+lr]
// P in that layout IS the A-fragment of mfma_16x16x16 for PV. O[q][d] accum fp32.
__global__ __launch_bounds__(256) void k_attn2(
    const float* __restrict__ QK,            // (8192,512) fp32; Q in cols 0..255
    const unsigned short* __restrict__ Kbf,  // [64][1024][32] bf16
    const unsigned short* __restrict__ Vtb,  // [64][32][1024] bf16
    const unsigned char* __restrict__ mask,  // (8192)
    float* __restrict__ O)                   // (8192,256)
{
  const int wv = threadIdx.x >> 6, lane = threadIdx.x & 63;
  const int qt = blockIdx.x * 4 + wv;
  const int bh = blockIdx.y;
  const int b = bh >> 3, h = bh & 7;
  const int q0 = qt << 4;
  const int lr = lane & 15, lg = lane >> 4;

  // Q B-fragment: Q[q0+lr][lg*8+j], fp32 -> bf16
  const float* qrow = QK + (size_t)(b*1024 + q0 + lr)*512 + h*32 + lg*8;
  bf16x8 qf;
  #pragma unroll
  for (int j=0;j<8;++j) qf[j] = (short)f2bf(qrow[j]);

  const unsigned short* kbase  = Kbf + (size_t)bh*32768 + lr*32 + lg*8;
  const unsigned short* vbase0 = Vtb + (size_t)bh*32768 + lr*1024 + lg*4;
  const unsigned short* vbase1 = vbase0 + 16*1024;
  const unsigned char*  mbase  = mask + b*1024 + lg*4;

  f32x4 accv0 = {0.f,0.f,0.f,0.f}, accv1 = {0.f,0.f,0.f,0.f};
  float m_run = -1e30f, l_run = 0.f;
  const float Cs = 0.17677669529663687f * 1.4426950408889634f; // 1/sqrt(32) * log2(e)

  for (int kt = 0; kt < 64; ++kt) {
    const int k0 = kt << 4;
    bf16x8 kf = *reinterpret_cast<const bf16x8*>(kbase + (size_t)k0*32);
    f32x4 z = {0.f,0.f,0.f,0.f};
    f32x4 st = __builtin_amdgcn_mfma_f32_16x16x32_bf16(kf, qf, z, 0, 0, 0);
    const unsigned mword = *reinterpret_cast<const unsigned*>(mbase + k0);
    float s[4];
    #pragma unroll
    for (int i=0;i<4;++i){
      float bias = ((mword >> (8*i)) & 255u) ? -2.0e9f : 0.f;
      s[i] = st[i]*Cs + bias;
    }
    float mc = fmaxf(fmaxf(s[0],s[1]), fmaxf(s[2],s[3]));
    mc = fmaxf(mc, __shfl_xor(mc, 16, 64));
    mc = fmaxf(mc, __shfl_xor(mc, 32, 64));
    if (!__all(mc <= m_run + 8.f)) {        // defer-max (T13), log2 domain
      float m_new = fmaxf(m_run, mc);
      float sc = fexp2(m_run - m_new);
      l_run *= sc;
      m_run = m_new;
      float sc0 = __shfl(sc, lg*4+0, 64);
      float sc1 = __shfl(sc, lg*4+1, 64);
      float sc2 = __shfl(sc, lg*4+2, 64);
      float sc3 = __shfl(sc, lg*4+3, 64);
      accv0[0]*=sc0; accv0[1]*=sc1; accv0[2]*=sc2; accv0[3]*=sc3;
      accv1[0]*=sc0; accv1[1]*=sc1; accv1[2]*=sc2; accv1[3]*=sc3;
    }
    float p[4], ps = 0.f;
    bf16x4 pb;
    #pragma unroll
    for (int i=0;i<4;++i){
      p[i] = fexp2(s[i] - m_run);
      ps += p[i];
      pb[i] = (short)f2bf(p[i]);
    }
    ps += __shfl_xor(ps, 16, 64);
    ps += __shfl_xor(ps, 32, 64);
    l_run += ps;
    bf16x4 vf0 = *reinterpret_cast<const bf16x4*>(vbase0 + k0);
    bf16x4 vf1 = *reinterpret_cast<const bf16x4*>(vbase1 + k0);
    accv0 = mfma16x16(pb, vf0, accv0);
    accv1 = mfma16x16(pb, vf1, accv1);
  }
  float li[4];
  #pragma unroll
  for (int i=0;i<4;++i) li[i] = 1.f / __shfl(l_run, lg*4+i, 64);
  float* orow = O + (size_t)(b*1024 + q0)*256 + h*32;
  #pragma unroll
  for (int i=0;i<4;++i){
    orow[(size_t)(lg*4+i)*256 + lr]      = accv0[i]*li[i];
    orow[(size_t)(lg*4+i)*256 + 16 + lr] = accv1[i]*li[i];
  }
}

// ---------------- fused residual-add + LayerNorm (rows of 256) ----------------
__global__ __launch_bounds__(256) void k_addln(
    const float* __restrict__ X, const float* __restrict__ Y,
    const float* __restrict__ g, const float* __restrict__ be,
    float* __restrict__ out)
{
  const int wave = threadIdx.x >> 6, lane = threadIdx.x & 63;
  const int row = blockIdx.x*4 + wave;
  const float4 x = reinterpret_cast<const float4*>(X + (size_t)row*256)[lane];
  const float4 y = reinterpret_cast<const float4*>(Y + (size_t)row*256)[lane];
  float4 v = f4add(x,y);
  float s = wredsum(v.x+v.y+v.z+v.w);
  const float mean = s * 0.00390625f;
  float4 d = make_float4(v.x-mean, v.y-mean, v.z-mean, v.w-mean);
  float sq = wredsum(d.x*d.x + d.y*d.y + d.z*d.z + d.w*d.w);
  const float rstd = rsqrtf(sq*0.00390625f + 1e-5f);
  const float4 gg = reinterpret_cast<const float4*>(g)[lane];
  const float4 bb = reinterpret_cast<const float4*>(be)[lane];
  float4 o = make_float4(d.x*rstd*gg.x + bb.x, d.y*rstd*gg.y + bb.y,
                         d.z*rstd*gg.z + bb.z, d.w*rstd*gg.w + bb.w);
  reinterpret_cast<float4*>(out + (size_t)row*256)[lane] = o;
}

// ---------------- deform: per-(b,q,h) softmax + bilinear weights ----------------
__global__ __launch_bounds__(256) void k_dwt(
    const float* __restrict__ offb,
    const float* __restrict__ attb,
    const float* __restrict__ refp,
    float* __restrict__ wbuf)
{
  const int idx = blockIdx.x*256 + threadIdx.x;
  if (idx >= B_*LQ_*NH_) return;
  const int h = idx & 7, bq = idx >> 3;
  const float* al = attb + (size_t)bq*96 + h*12;
  float lg[12];
  float mx = -INFINITY;
  #pragma unroll
  for (int i=0;i<12;++i){ lg[i] = al[i]; mx = fmaxf(mx, lg[i]); }
  float se = 0.f;
  #pragma unroll
  for (int i=0;i<12;++i){ lg[i] = __expf(lg[i]-mx); se += lg[i]; }
  const float inv = 1.f/se;
  const float rx = refp[(size_t)bq*2+0], ry = refp[(size_t)bq*2+1];
  const float* ofs = offb + (size_t)bq*192 + h*24;
  float* wout = wbuf + (size_t)idx*96;
  int* iout = reinterpret_cast<int*>(wout);
  const int HH[3]={100,50,25}, WW[3]={100,50,25}, SS[3]={0,10000,12500};
  const int vb = (bq >> 10) * LIN_;
  #pragma unroll
  for (int l=0;l<3;++l){
    const float Wf = (float)WW[l], Hf = (float)HH[l];
    const int Wi = WW[l], Hi = HH[l], s0 = SS[l];
    #pragma unroll
    for (int p=0;p<4;++p){
      const int pt = l*4+p;
      const float ox = ofs[pt*2+0], oy = ofs[pt*2+1];
      const float x = (rx + ox/Wf)*Wf - 0.5f;
      const float y = (ry + oy/Hf)*Hf - 0.5f;
      const float x0f = floorf(x), y0f = floorf(y);
      const float wx = x - x0f, wy = y - y0f;
      const int x0 = (int)x0f, y0 = (int)y0f;
      const float aw = lg[pt]*inv;
      const float w00=(1.f-wy)*(1.f-wx)*aw, w01=(1.f-wy)*wx*aw;
      const float w10=wy*(1.f-wx)*aw,       w11=wy*wx*aw;
      const int xs0 = min(max(x0,0),Wi-1),   xs1 = min(max(x0+1,0),Wi-1);
      const int ys0 = min(max(y0,0),Hi-1),   ys1 = min(max(y0+1,0),Hi-1);
      const bool vx0 = (x0>=0)&&(x0<Wi),     vx1 = (x0+1>=0)&&(x0+1<Wi);
      const bool vy0 = (y0>=0)&&(y0<Hi),     vy1 = (y0+1>=0)&&(y0+1<Hi);
      iout[pt*8+0] = vb + s0 + ys0*Wi + xs0;
      iout[pt*8+1] = vb + s0 + ys0*Wi + xs1;
      iout[pt*8+2] = vb + s0 + ys1*Wi + xs0;
      iout[pt*8+3] = vb + s0 + ys1*Wi + xs1;
      wout[pt*8+4] = (vy0&&vx0)? w00 : 0.f;
      wout[pt*8+5] = (vy0&&vx1)? w01 : 0.f;
      wout[pt*8+6] = (vy1&&vx0)? w10 : 0.f;
      wout[pt*8+7] = (vy1&&vx1)? w11 : 0.f;
    }
  }
}

// ---------------- deform: gather & accumulate ----------------
__global__ __launch_bounds__(256) void k_dgather(
    const float* __restrict__ vproj,
    const float* __restrict__ wbuf,
    float* __restrict__ out)
{
  const int t = blockIdx.x*256 + threadIdx.x;
  const int col = t & 255;
  const int gh = t >> 5;
  const float* wp = wbuf + (size_t)gh*96;
  const int* ip = reinterpret_cast<const int*>(wp);
  float acc = 0.f;
  #pragma unroll
  for (int pt=0; pt<12; ++pt){
    const int b0 = pt*8;
    acc = fmaf(wp[b0+4], vproj[(size_t)ip[b0+0]*256 + col], acc);
    acc = fmaf(wp[b0+5], vproj[(size_t)ip[b0+1]*256 + col], acc);
    acc = fmaf(wp[b0+6], vproj[(size_t)ip[b0+2]*256 + col], acc);
    acc = fmaf(wp[b0+7], vproj[(size_t)ip[b0+3]*256 + col], acc);
  }
  out[t] = acc;
}

extern "C" void kernel_launch(void* const* d_in, const int* in_sizes, int n_in,
                              void* d_out, int out_size, void* d_ws, size_t ws_size,
                              hipStream_t stream)
{
  const float* qe      = (const float*)d_in[0];
  const unsigned char* qmask = (const unsigned char*)d_in[1];
  const float* qo      = (const float*)d_in[2];
  const float* values  = (const float*)d_in[3];
  const float* refp    = (const float*)d_in[4];
  const float* rp      = (const float*)d_in[5];
  const float* rf      = (const float*)d_in[6];
  const float* sa_in_w = (const float*)d_in[10];
  const float* sa_in_b = (const float*)d_in[11];
  const float* sa_out_w= (const float*)d_in[12];
  const float* sa_out_b= (const float*)d_in[13];
  const float* sa_ln1_g= (const float*)d_in[14];
  const float* sa_ln1_b= (const float*)d_in[15];
  const float* sa_l1_w = (const float*)d_in[16];
  const float* sa_l1_b = (const float*)d_in[17];
  const float* sa_l2_w = (const float*)d_in[18];
  const float* sa_l2_b = (const float*)d_in[19];
  const float* sa_ln2_g= (const float*)d_in[20];
  const float* sa_ln2_b= (const float*)d_in[21];
  const float* da_val_w= (const float*)d_in[22];
  const float* da_val_b= (const float*)d_in[23];
  const float* da_off_w= (const float*)d_in[24];
  const float* da_off_b= (const float*)d_in[25];
  const float* da_att_w= (const float*)d_in[26];
  const float* da_att_b= (const float*)d_in[27];
  const float* da_out_w= (const float*)d_in[28];
  const float* da_out_b= (const float*)d_in[29];
  const float* ln1_g   = (const float*)d_in[30];
  const float* ln1_b   = (const float*)d_in[31];
  const float* ff1_w   = (const float*)d_in[32];
  const float* ff1_b   = (const float*)d_in[33];
  const float* ff2_w   = (const float*)d_in[34];
  const float* ff2_b   = (const float*)d_in[35];
  const float* ln2_g   = (const float*)d_in[36];
  const float* ln2_b   = (const float*)d_in[37];

  float* Wk = (float*)d_ws;
  const size_t M2 = 2097152;          // B*LQ*D
  float* A  = Wk;                     // src / tgt (persistent)
  float* Bq = Wk + M2;                // q / dq
  float* F  = Wk + 2*M2;              // gemm-out tmp before LN
  float* G  = Wk + 3*M2;              // 8M multi-use region
  float* H  = Wk + 7*M2;              // vproj: 105000*256
  float* I  = H + 26880000;           // off logits
  float* J  = I + 1572864;            // att logits
  float* Kw = J + 786432;             // bilinear weights
  float* qk = G;                      // (8192,512)  == G..G+2*M2
  float* vp = G + 4*M2;               // (8192,256)
  float* ao = G + 6*M2;               // (8192,256)
  unsigned short* Kbf = (unsigned short*)(G + 2*M2); // 2,097,152 bf16 (4MB)
  unsigned short* Vtb = Kbf + 2097152;               // 2,097,152 bf16 (4MB)

  dim3 blk(256);
  k_prep<<<2048, blk, 0, stream>>>((const float4*)qe,(const float4*)rf,
                                   (const float4*)qo,(const float4*)rp,
                                   (float4*)A,(float4*)Bq);
  k_gemm<<<dim3(8,128), blk, 0, stream>>>(Bq,256, sa_in_w,768, sa_in_b, qk,512, 8192,512,256, 0);
  k_gemm<<<dim3(4,128), blk, 0, stream>>>(A,256, sa_in_w+512,768, sa_in_b+512, vp,256, 8192,256,256, 0);
  k_cvt<<<128, blk, 0, stream>>>(qk, vp, Kbf, Vtb);
  k_attn2<<<dim3(16,64), blk, 0, stream>>>(qk, Kbf, Vtb, qmask, ao);
  k_gemm<<<dim3(4,128), blk, 0, stream>>>(ao,256, sa_out_w,256, sa_out_b, F,256, 8192,256,256, 0);
  k_addln<<<2048, blk, 0, stream>>>(A, F, sa_ln1_g, sa_ln1_b, A);
  k_gemm<<<dim3(16,128), blk, 0, stream>>>(A,256, sa_l1_w,1024, sa_l1_b, G,1024, 8192,1024,256, 1);
  k_gemm<<<dim3(4,128), blk, 0, stream>>>(G,1024, sa_l2_w,256, sa_l2_b, F,256, 8192,256,1024, 0);
  k_addln<<<2048, blk, 0, stream>>>(A, F, sa_ln2_g, sa_ln2_b, A);
  k_dq<<<2048, blk, 0, stream>>>((const float4*)A,(const float4*)qo,
                                 (const float4*)rp,(const float4*)rf,(float4*)Bq);
  k_gemm<<<dim3(4,1641), blk, 0, stream>>>(values,256, da_val_w,256, da_val_b, H,256, 105000,256,256, 0);
  k_gemm<<<dim3(3,128), blk, 0, stream>>>(Bq,256, da_off_w,192, da_off_b, I,192, 8192,192,256, 0);
  k_gemm<<<dim3(2,128), blk, 0, stream>>>(Bq,256, da_att_w,96, da_att_b, J,96, 8192,96,256, 0);
  k_dwt<<<256, blk, 0, stream>>>(I, J, refp, Kw);
  k_dgather<<<8192, blk, 0, stream>>>(H, Kw, G);
  k_gemm<<<dim3(4,128), blk, 0, stream>>>(G,256, da_out_w,256, da_out_b, F,256, 8192,256,256, 0);
  k_addln<<<2048, blk, 0, stream>>>(A, F, ln1_g, ln1_b, A);
  k_gemm<<<dim3(16,128), blk, 0, stream>>>(A,256, ff1_w,1024, ff1_b, G,1024, 8192,1024,256, 1);
  k_gemm<<<dim3(4,128), blk, 0, stream>>>(G,1024, ff2_w,256, ff2_b, F,256, 8192,256,1024, 0);
  k_addln<<<2048, blk, 0, stream>>>(A, F, ln2_g, ln2_b, (float*)d_out);
}

// Round 3
// 434.107 us; speedup vs baseline: 3.7910x; 1.9675x over previous
//
#include <hip/hip_runtime.h>
#include <math.h>

#define B_   8
#define LQ_  1024
#define D_   256
#define NH_  8
#define DH_  32
#define LIN_ 13125

typedef __attribute__((ext_vector_type(4))) float f32x4;
typedef __attribute__((ext_vector_type(8))) short bf16x8;
typedef __attribute__((ext_vector_type(4))) short bf16x4;

__device__ __forceinline__ float4 f4add(float4 a, float4 b){
  return make_float4(a.x+b.x, a.y+b.y, a.z+b.z, a.w+b.w);
}
__device__ __forceinline__ float wredsum(float v){
  #pragma unroll
  for (int o=1;o<64;o<<=1) v += __shfl_xor(v,o,64);
  return v;
}
__device__ __forceinline__ unsigned short f2bf(float f){
  unsigned u = __float_as_uint(f);
  unsigned r = (u + 0x7fffu + ((u>>16)&1u)) >> 16;
  return (unsigned short)r;
}
__device__ __forceinline__ float bf2f(unsigned short u){
  return __uint_as_float(((unsigned)u)<<16);
}
__device__ __forceinline__ unsigned pk2(float a, float b){
  return (unsigned)f2bf(a) | ((unsigned)f2bf(b)<<16);
}
__device__ __forceinline__ float fexp2(float x){
#if __has_builtin(__builtin_amdgcn_exp2f)
  return __builtin_amdgcn_exp2f(x);
#else
  return exp2f(x);
#endif
}
__device__ __forceinline__ f32x4 mfma16x16(bf16x4 a, bf16x4 b, f32x4 c){
#if __has_builtin(__builtin_amdgcn_mfma_f32_16x16x16_bf16)
  return __builtin_amdgcn_mfma_f32_16x16x16_bf16(a, b, c, 0, 0, 0);
#else
  asm volatile("s_nop 1\n\tv_mfma_f32_16x16x16_bf16 %0, %1, %2, %0"
               : "+v"(c) : "v"(a), "v"(b));
  return c;
#endif
}
__device__ __forceinline__ void gload16(const void* g, void* l){
  __builtin_amdgcn_global_load_lds(
      (const __attribute__((address_space(1))) void*)g,
      (__attribute__((address_space(3))) void*)l, 16, 0, 0);
}

// ---------------- elementwise prep ----------------
__global__ __launch_bounds__(256) void k_prep(
    const float4* __restrict__ qe, const float4* __restrict__ rf,
    const float4* __restrict__ qo, const float4* __restrict__ rp,
    float4* __restrict__ src, uint2* __restrict__ srcb, uint2* __restrict__ qb)
{
  int i = blockIdx.x*256 + threadIdx.x;
  float4 s = f4add(qe[i], rf[i]);
  src[i] = s;
  float4 q = f4add(s, f4add(qo[i], rp[i]));
  srcb[i] = make_uint2(pk2(s.x,s.y), pk2(s.z,s.w));
  qb[i]   = make_uint2(pk2(q.x,q.y), pk2(q.z,q.w));
}

__global__ __launch_bounds__(256) void k_dq(
    const float4* __restrict__ tgt, const float4* __restrict__ qo,
    const float4* __restrict__ rp, const float4* __restrict__ rf,
    float4* __restrict__ dq)
{
  int i = blockIdx.x*256 + threadIdx.x;
  dq[i] = f4add(f4add(tgt[i], qo[i]), f4add(rp[i], rf[i]));
}

// ---------------- fp32 GEMM (kept for small off/att projections) ----------------
__global__ __launch_bounds__(256) void k_gemm(
    const float* __restrict__ A, int lda,
    const float* __restrict__ Wt, int ldw,
    const float* __restrict__ bias,
    float* __restrict__ C, int ldc,
    int M, int N, int K, int relu)
{
  __shared__ float As[16][68];
  __shared__ float Bs[16][68];
  const int t  = threadIdx.x;
  const int tx = t & 15, ty = t >> 4;
  const int m0 = blockIdx.y * 64;
  const int n0 = blockIdx.x * 64;
  const int la_m = t >> 2;
  const int la_k = (t & 3) << 2;
  const int lb_k = t >> 4;
  const int lb_n = (t & 15) << 2;
  float acc[4][4] = {};
  for (int kb = 0; kb < K; kb += 16) {
    float4 av = make_float4(0.f,0.f,0.f,0.f);
    const int am = m0 + la_m;
    if (am < M)
      av = *reinterpret_cast<const float4*>(A + (size_t)am*lda + kb + la_k);
    As[la_k+0][la_m]=av.x; As[la_k+1][la_m]=av.y;
    As[la_k+2][la_m]=av.z; As[la_k+3][la_m]=av.w;
    float4 bv = make_float4(0.f,0.f,0.f,0.f);
    {
      const float* wr = Wt + (size_t)(kb + lb_k)*ldw;
      const int bn = n0 + lb_n;
      if (bn + 3 < N) {
        bv = *reinterpret_cast<const float4*>(wr + bn);
      } else {
        if (bn+0 < N) bv.x = wr[bn+0];
        if (bn+1 < N) bv.y = wr[bn+1];
        if (bn+2 < N) bv.z = wr[bn+2];
      }
    }
    *reinterpret_cast<float4*>(&Bs[lb_k][lb_n]) = bv;
    __syncthreads();
    #pragma unroll
    for (int k = 0; k < 16; ++k) {
      float4 a4 = *reinterpret_cast<const float4*>(&As[k][ty<<2]);
      float4 b4 = *reinterpret_cast<const float4*>(&Bs[k][tx<<2]);
      float aa[4] = {a4.x,a4.y,a4.z,a4.w};
      float bb[4] = {b4.x,b4.y,b4.z,b4.w};
      #pragma unroll
      for (int i=0;i<4;++i)
        #pragma unroll
        for (int j=0;j<4;++j)
          acc[i][j] = fmaf(aa[i], bb[j], acc[i][j]);
    }
    __syncthreads();
  }
  #pragma unroll
  for (int i=0;i<4;++i){
    const int row = m0 + (ty<<2) + i;
    if (row >= M) continue;
    #pragma unroll
    for (int j=0;j<4;++j){
      const int col = n0 + (tx<<2) + j;
      if (col >= N) continue;
      float v = acc[i][j] + bias[col];
      if (relu) v = fmaxf(v, 0.f);
      C[(size_t)row*ldc + col] = v;
    }
  }
}

// ---------------- batched weight transpose->bf16: Wt[N][K] from W[K][N] ----------------
struct WEnt { const float* s; unsigned short* d; int K; int N; };
struct WPack { WEnt e[8]; };
__global__ __launch_bounds__(256) void k_wtcvt(WPack p)
{
  __shared__ float sm[32][33];
  WEnt w = p.e[blockIdx.y];
  const int tk = w.K >> 5, tn = w.N >> 5;
  const int nt = tk * tn;
  const int r = threadIdx.x >> 5, c = threadIdx.x & 31;
  for (int tile = blockIdx.x; tile < nt; tile += gridDim.x) {
    const int ti = tile / tn, tj = tile % tn;
    #pragma unroll
    for (int rr = r; rr < 32; rr += 8)
      sm[rr][c] = w.s[(size_t)(ti*32+rr)*w.N + tj*32 + c];
    __syncthreads();
    #pragma unroll
    for (int rr = r; rr < 32; rr += 8)
      w.d[(size_t)(tj*32+rr)*w.K + ti*32 + c] = f2bf(sm[c][rr]);
    __syncthreads();
  }
}

// ---------------- fp32 -> bf16 bulk convert (8 elems/thread) ----------------
__global__ __launch_bounds__(256) void k_f2b8(
    const float4* __restrict__ in, uint4* __restrict__ out)
{
  const int i = blockIdx.x*256 + threadIdx.x;
  float4 a = in[2*i], b = in[2*i+1];
  out[i] = make_uint4(pk2(a.x,a.y), pk2(a.z,a.w), pk2(b.x,b.y), pk2(b.z,b.w));
}

// ---------------- bf16 MFMA GEMM: C = A(bf16) @ Wt(bf16,[N][K])^T + bias ----------------
// 128x128 tile, BK=32, 4 waves (2x2 of 64x64), dbuf LDS via global_load_lds w=16,
// XOR chunk swizzle (inverse-swizzled global source, swizzled ds_read).
template<bool BF16OUT>
__global__ __launch_bounds__(256) void k_gemm_bf(
    const unsigned short* __restrict__ A, int lda,
    const unsigned short* __restrict__ Wt,
    const float* __restrict__ bias,
    float* __restrict__ Cf, unsigned short* __restrict__ Cb, int ldc,
    int M, int N, int K, int relu)
{
  __shared__ unsigned short As[2][4096];
  __shared__ unsigned short Bs[2][4096];
  const int t = threadIdx.x;
  const int m0 = blockIdx.y * 128;
  const int n0 = blockIdx.x * 128;
  const int w  = t >> 6, lane = t & 63;
  const int lr = lane & 15, lg = lane >> 4;
  const int wm = (w & 1) * 64, wn = (w >> 1) * 64;

  // staging geometry: 512 chunks of 16B per tile; thread t owns chunks t and t+256
  const int rowc  = t >> 2;                         // 0..63
  const int cbs8  = (((t & 3) ^ ((t >> 2) & 3)) << 3); // swizzled source k-offset (elems)
  const size_t ra0 = (size_t)min(m0 + rowc,      M-1) * lda;
  const size_t ra1 = (size_t)min(m0 + rowc + 64, M-1) * lda;
  const size_t rb0 = (size_t)(n0 + rowc)      * K;
  const size_t rb1 = (size_t)(n0 + rowc + 64) * K;
  unsigned short* la0[2] = { &As[0][(w<<9)],        &As[1][(w<<9)] };
  unsigned short* la1[2] = { &As[0][2048+(w<<9)],   &As[1][2048+(w<<9)] };
  unsigned short* lb0[2] = { &Bs[0][(w<<9)],        &Bs[1][(w<<9)] };
  unsigned short* lb1[2] = { &Bs[0][2048+(w<<9)],   &Bs[1][2048+(w<<9)] };

  f32x4 acc[4][4];
  #pragma unroll
  for (int i=0;i<4;++i)
    #pragma unroll
    for (int j=0;j<4;++j) acc[i][j] = (f32x4){0.f,0.f,0.f,0.f};

  const int cswz = ((lg ^ (lr & 3)) << 3);
  const int nt = K >> 5;

  // stage K-step 0 into buf 0
  {
    const int kb = 0;
    gload16(A  + ra0 + kb + cbs8, la0[0]);
    gload16(A  + ra1 + kb + cbs8, la1[0]);
    gload16(Wt + rb0 + kb + cbs8, lb0[0]);
    gload16(Wt + rb1 + kb + cbs8, lb1[0]);
  }
  for (int ks = 0; ks < nt; ++ks) {
    const int cur = ks & 1;
    __syncthreads();                       // drains vmcnt: stage(ks) landed
    if (ks + 1 < nt) {
      const int kb = (ks + 1) << 5;
      const int nb = cur ^ 1;
      gload16(A  + ra0 + kb + cbs8, la0[nb]);
      gload16(A  + ra1 + kb + cbs8, la1[nb]);
      gload16(Wt + rb0 + kb + cbs8, lb0[nb]);
      gload16(Wt + rb1 + kb + cbs8, lb1[nb]);
    }
    bf16x8 af[4], bfr[4];
    #pragma unroll
    for (int mi=0;mi<4;++mi)
      af[mi]  = *reinterpret_cast<const bf16x8*>(&As[cur][(wm+mi*16+lr)*32 + cswz]);
    #pragma unroll
    for (int ni=0;ni<4;++ni)
      bfr[ni] = *reinterpret_cast<const bf16x8*>(&Bs[cur][(wn+ni*16+lr)*32 + cswz]);
    #pragma unroll
    for (int mi=0;mi<4;++mi)
      #pragma unroll
      for (int ni=0;ni<4;++ni)
        acc[mi][ni] = __builtin_amdgcn_mfma_f32_16x16x32_bf16(af[mi], bfr[ni], acc[mi][ni], 0, 0, 0);
  }

  float bs[4];
  #pragma unroll
  for (int ni=0;ni<4;++ni) bs[ni] = bias[n0 + wn + ni*16 + lr];
  #pragma unroll
  for (int mi=0;mi<4;++mi){
    #pragma unroll
    for (int i=0;i<4;++i){
      const int row = m0 + wm + mi*16 + lg*4 + i;
      if (row >= M) continue;
      #pragma unroll
      for (int ni=0;ni<4;++ni){
        const int col = n0 + wn + ni*16 + lr;
        float v = acc[mi][ni][i] + bs[ni];
        if (relu) v = fmaxf(v, 0.f);
        if (BF16OUT) Cb[(size_t)row*ldc + col] = f2bf(v);
        else         Cf[(size_t)row*ldc + col] = v;
      }
    }
  }
}

// ---------------- convert K -> bf16 [bh][1024][32]; V -> bf16 transposed [bh][32][1024] ----------------
__global__ __launch_bounds__(256) void k_cvt(
    const float* __restrict__ QKsrc,
    const float* __restrict__ VP,
    unsigned short* __restrict__ Kbf,
    unsigned short* __restrict__ Vtb)
{
  __shared__ unsigned short vt[256][65];
  const int r0 = blockIdx.x * 64;
  const int b  = r0 >> 10;
  const int rl0 = r0 & 1023;
  const int t = threadIdx.x;
  for (int idx = t; idx < 64*256; idx += 256) {
    int r = idx >> 8, c = idx & 255;
    float v = QKsrc[(size_t)(r0 + r)*512 + 256 + c];
    int h = c >> 5, d = c & 31;
    Kbf[(size_t)(b*8 + h)*32768 + (size_t)(rl0 + r)*32 + d] = f2bf(v);
  }
  for (int idx = t; idx < 64*256; idx += 256) {
    int r = idx >> 8, c = idx & 255;
    vt[c][r] = f2bf(VP[(size_t)(r0 + r)*256 + c]);
  }
  __syncthreads();
  for (int idx = t; idx < 64*256; idx += 256) {
    int dall = idx >> 6, r = idx & 63;
    Vtb[(size_t)(b*8 + (dall>>5))*32768 + (size_t)(dall & 31)*1024 + rl0 + r] = vt[dall][r];
  }
}

// ---------------- MFMA flash attention (bf16 out) ----------------
__global__ __launch_bounds__(256) void k_attn2(
    const float* __restrict__ QK,
    const unsigned short* __restrict__ Kbf,
    const unsigned short* __restrict__ Vtb,
    const unsigned char* __restrict__ mask,
    unsigned short* __restrict__ Ob)
{
  const int wv = threadIdx.x >> 6, lane = threadIdx.x & 63;
  const int qt = blockIdx.x * 4 + wv;
  const int bh = blockIdx.y;
  const int b = bh >> 3, h = bh & 7;
  const int q0 = qt << 4;
  const int lr = lane & 15, lg = lane >> 4;

  const float* qrow = QK + (size_t)(b*1024 + q0 + lr)*512 + h*32 + lg*8;
  bf16x8 qf;
  #pragma unroll
  for (int j=0;j<8;++j) qf[j] = (short)f2bf(qrow[j]);

  const unsigned short* kbase  = Kbf + (size_t)bh*32768 + lr*32 + lg*8;
  const unsigned short* vbase0 = Vtb + (size_t)bh*32768 + lr*1024 + lg*4;
  const unsigned short* vbase1 = vbase0 + 16*1024;
  const unsigned char*  mbase  = mask + b*1024 + lg*4;

  f32x4 accv0 = {0.f,0.f,0.f,0.f}, accv1 = {0.f,0.f,0.f,0.f};
  float m_run = -1e30f, l_run = 0.f;
  const float Cs = 0.17677669529663687f * 1.4426950408889634f;

  for (int kt = 0; kt < 64; ++kt) {
    const int k0 = kt << 4;
    bf16x8 kf = *reinterpret_cast<const bf16x8*>(kbase + (size_t)k0*32);
    f32x4 z = {0.f,0.f,0.f,0.f};
    f32x4 st = __builtin_amdgcn_mfma_f32_16x16x32_bf16(kf, qf, z, 0, 0, 0);
    const unsigned mword = *reinterpret_cast<const unsigned*>(mbase + k0);
    float s[4];
    #pragma unroll
    for (int i=0;i<4;++i){
      float bias = ((mword >> (8*i)) & 255u) ? -2.0e9f : 0.f;
      s[i] = st[i]*Cs + bias;
    }
    float mc = fmaxf(fmaxf(s[0],s[1]), fmaxf(s[2],s[3]));
    mc = fmaxf(mc, __shfl_xor(mc, 16, 64));
    mc = fmaxf(mc, __shfl_xor(mc, 32, 64));
    if (!__all(mc <= m_run + 8.f)) {
      float m_new = fmaxf(m_run, mc);
      float sc = fexp2(m_run - m_new);
      l_run *= sc;
      m_run = m_new;
      float sc0 = __shfl(sc, lg*4+0, 64);
      float sc1 = __shfl(sc, lg*4+1, 64);
      float sc2 = __shfl(sc, lg*4+2, 64);
      float sc3 = __shfl(sc, lg*4+3, 64);
      accv0[0]*=sc0; accv0[1]*=sc1; accv0[2]*=sc2; accv0[3]*=sc3;
      accv1[0]*=sc0; accv1[1]*=sc1; accv1[2]*=sc2; accv1[3]*=sc3;
    }
    float p[4], ps = 0.f;
    bf16x4 pb;
    #pragma unroll
    for (int i=0;i<4;++i){
      p[i] = fexp2(s[i] - m_run);
      ps += p[i];
      pb[i] = (short)f2bf(p[i]);
    }
    ps += __shfl_xor(ps, 16, 64);
    ps += __shfl_xor(ps, 32, 64);
    l_run += ps;
    bf16x4 vf0 = *reinterpret_cast<const bf16x4*>(vbase0 + k0);
    bf16x4 vf1 = *reinterpret_cast<const bf16x4*>(vbase1 + k0);
    accv0 = mfma16x16(pb, vf0, accv0);
    accv1 = mfma16x16(pb, vf1, accv1);
  }
  float li[4];
  #pragma unroll
  for (int i=0;i<4;++i) li[i] = 1.f / __shfl(l_run, lg*4+i, 64);
  unsigned short* orow = Ob + (size_t)(b*1024 + q0)*256 + h*32;
  #pragma unroll
  for (int i=0;i<4;++i){
    orow[(size_t)(lg*4+i)*256 + lr]      = f2bf(accv0[i]*li[i]);
    orow[(size_t)(lg*4+i)*256 + 16 + lr] = f2bf(accv1[i]*li[i]);
  }
}

// ---------------- fused residual-add + LayerNorm (fp32 out + optional bf16 out) ----------------
__global__ __launch_bounds__(256) void k_addln(
    const float* __restrict__ X, const float* __restrict__ Y,
    const float* __restrict__ g, const float* __restrict__ be,
    float* __restrict__ out, uint2* __restrict__ bout)
{
  const int wave = threadIdx.x >> 6, lane = threadIdx.x & 63;
  const int row = blockIdx.x*4 + wave;
  const float4 x = reinterpret_cast<const float4*>(X + (size_t)row*256)[lane];
  const float4 y = reinterpret_cast<const float4*>(Y + (size_t)row*256)[lane];
  float4 v = f4add(x,y);
  float s = wredsum(v.x+v.y+v.z+v.w);
  const float mean = s * 0.00390625f;
  float4 d = make_float4(v.x-mean, v.y-mean, v.z-mean, v.w-mean);
  float sq = wredsum(d.x*d.x + d.y*d.y + d.z*d.z + d.w*d.w);
  const float rstd = rsqrtf(sq*0.00390625f + 1e-5f);
  const float4 gg = reinterpret_cast<const float4*>(g)[lane];
  const float4 bb = reinterpret_cast<const float4*>(be)[lane];
  float4 o = make_float4(d.x*rstd*gg.x + bb.x, d.y*rstd*gg.y + bb.y,
                         d.z*rstd*gg.z + bb.z, d.w*rstd*gg.w + bb.w);
  reinterpret_cast<float4*>(out + (size_t)row*256)[lane] = o;
  if (bout) bout[(size_t)row*64 + lane] = make_uint2(pk2(o.x,o.y), pk2(o.z,o.w));
}

// ---------------- deform: per-(b,q,h) softmax + bilinear weights ----------------
__global__ __launch_bounds__(256) void k_dwt(
    const float* __restrict__ offb,
    const float* __restrict__ attb,
    const float* __restrict__ refp,
    float* __restrict__ wbuf)
{
  const int idx = blockIdx.x*256 + threadIdx.x;
  if (idx >= B_*LQ_*NH_) return;
  const int h = idx & 7, bq = idx >> 3;
  const float* al = attb + (size_t)bq*96 + h*12;
  float lg[12];
  float mx = -INFINITY;
  #pragma unroll
  for (int i=0;i<12;++i){ lg[i] = al[i]; mx = fmaxf(mx, lg[i]); }
  float se = 0.f;
  #pragma unroll
  for (int i=0;i<12;++i){ lg[i] = __expf(lg[i]-mx); se += lg[i]; }
  const float inv = 1.f/se;
  const float rx = refp[(size_t)bq*2+0], ry = refp[(size_t)bq*2+1];
  const float* ofs = offb + (size_t)bq*192 + h*24;
  float* wout = wbuf + (size_t)idx*96;
  int* iout = reinterpret_cast<int*>(wout);
  const int HH[3]={100,50,25}, WW[3]={100,50,25}, SS[3]={0,10000,12500};
  const int vb = (bq >> 10) * LIN_;
  #pragma unroll
  for (int l=0;l<3;++l){
    const float Wf = (float)WW[l], Hf = (float)HH[l];
    const int Wi = WW[l], Hi = HH[l], s0 = SS[l];
    #pragma unroll
    for (int p=0;p<4;++p){
      const int pt = l*4+p;
      const float ox = ofs[pt*2+0], oy = ofs[pt*2+1];
      const float x = (rx + ox/Wf)*Wf - 0.5f;
      const float y = (ry + oy/Hf)*Hf - 0.5f;
      const float x0f = floorf(x), y0f = floorf(y);
      const float wx = x - x0f, wy = y - y0f;
      const int x0 = (int)x0f, y0 = (int)y0f;
      const float aw = lg[pt]*inv;
      const float w00=(1.f-wy)*(1.f-wx)*aw, w01=(1.f-wy)*wx*aw;
      const float w10=wy*(1.f-wx)*aw,       w11=wy*wx*aw;
      const int xs0 = min(max(x0,0),Wi-1),   xs1 = min(max(x0+1,0),Wi-1);
      const int ys0 = min(max(y0,0),Hi-1),   ys1 = min(max(y0+1,0),Hi-1);
      const bool vx0 = (x0>=0)&&(x0<Wi),     vx1 = (x0+1>=0)&&(x0+1<Wi);
      const bool vy0 = (y0>=0)&&(y0<Hi),     vy1 = (y0+1>=0)&&(y0+1<Hi);
      iout[pt*8+0] = vb + s0 + ys0*Wi + xs0;
      iout[pt*8+1] = vb + s0 + ys0*Wi + xs1;
      iout[pt*8+2] = vb + s0 + ys1*Wi + xs0;
      iout[pt*8+3] = vb + s0 + ys1*Wi + xs1;
      wout[pt*8+4] = (vy0&&vx0)? w00 : 0.f;
      wout[pt*8+5] = (vy0&&vx1)? w01 : 0.f;
      wout[pt*8+6] = (vy1&&vx0)? w10 : 0.f;
      wout[pt*8+7] = (vy1&&vx1)? w11 : 0.f;
    }
  }
}

// ---------------- deform: gather & accumulate (bf16 in/out) ----------------
__global__ __launch_bounds__(256) void k_dgather(
    const unsigned short* __restrict__ vproj,
    const float* __restrict__ wbuf,
    unsigned short* __restrict__ outb)
{
  const int t = blockIdx.x*256 + threadIdx.x;
  const int col = t & 255;
  const int gh = t >> 5;
  const float* wp = wbuf + (size_t)gh*96;
  const int* ip = reinterpret_cast<const int*>(wp);
  float acc = 0.f;
  #pragma unroll
  for (int pt=0; pt<12; ++pt){
    const int b0 = pt*8;
    acc = fmaf(wp[b0+4], bf2f(vproj[(size_t)ip[b0+0]*256 + col]), acc);
    acc = fmaf(wp[b0+5], bf2f(vproj[(size_t)ip[b0+1]*256 + col]), acc);
    acc = fmaf(wp[b0+6], bf2f(vproj[(size_t)ip[b0+2]*256 + col]), acc);
    acc = fmaf(wp[b0+7], bf2f(vproj[(size_t)ip[b0+3]*256 + col]), acc);
  }
  outb[t] = f2bf(acc);
}

extern "C" void kernel_launch(void* const* d_in, const int* in_sizes, int n_in,
                              void* d_out, int out_size, void* d_ws, size_t ws_size,
                              hipStream_t stream)
{
  const float* qe      = (const float*)d_in[0];
  const unsigned char* qmask = (const unsigned char*)d_in[1];
  const float* qo      = (const float*)d_in[2];
  const float* values  = (const float*)d_in[3];
  const float* refp    = (const float*)d_in[4];
  const float* rp      = (const float*)d_in[5];
  const float* rf      = (const float*)d_in[6];
  const float* sa_in_w = (const float*)d_in[10];
  const float* sa_in_b = (const float*)d_in[11];
  const float* sa_out_w= (const float*)d_in[12];
  const float* sa_out_b= (const float*)d_in[13];
  const float* sa_ln1_g= (const float*)d_in[14];
  const float* sa_ln1_b= (const float*)d_in[15];
  const float* sa_l1_w = (const float*)d_in[16];
  const float* sa_l1_b = (const float*)d_in[17];
  const float* sa_l2_w = (const float*)d_in[18];
  const float* sa_l2_b = (const float*)d_in[19];
  const float* sa_ln2_g= (const float*)d_in[20];
  const float* sa_ln2_b= (const float*)d_in[21];
  const float* da_val_w= (const float*)d_in[22];
  const float* da_val_b= (const float*)d_in[23];
  const float* da_off_w= (const float*)d_in[24];
  const float* da_off_b= (const float*)d_in[25];
  const float* da_att_w= (const float*)d_in[26];
  const float* da_att_b= (const float*)d_in[27];
  const float* da_out_w= (const float*)d_in[28];
  const float* da_out_b= (const float*)d_in[29];
  const float* ln1_g   = (const float*)d_in[30];
  const float* ln1_b   = (const float*)d_in[31];
  const float* ff1_w   = (const float*)d_in[32];
  const float* ff1_b   = (const float*)d_in[33];
  const float* ff2_w   = (const float*)d_in[34];
  const float* ff2_b   = (const float*)d_in[35];
  const float* ln2_g   = (const float*)d_in[36];
  const float* ln2_b   = (const float*)d_in[37];

  float* Wk = (float*)d_ws;
  const size_t MEG = 1u<<20;
  float* A   = Wk;                                    // 2M f32 (src/tgt)
  float* F   = Wk + 2*MEG;                            // 2M f32
  unsigned short* Ab   = (unsigned short*)(Wk + 4*MEG);  // bf16 of A
  unsigned short* hidb = (unsigned short*)(Wk + 5*MEG);  // 8192x1024 bf16
  unsigned short* WT   = (unsigned short*)(Wk + 9*MEG);  // transposed weights
  // union region (sa-phase)
  unsigned short* qb   = (unsigned short*)(Wk + 10*MEG);
  unsigned short* srcb = (unsigned short*)(Wk + 11*MEG);
  float* qk = Wk + 12*MEG;                            // 8192x512
  float* vp = Wk + 16*MEG;                            // 8192x256
  unsigned short* Kbf = (unsigned short*)(Wk + 18*MEG);
  unsigned short* Vtb = (unsigned short*)(Wk + 19*MEG);
  unsigned short* aob = (unsigned short*)(Wk + 20*MEG);
  // union region (deform-phase)
  float* dq = Wk + 10*MEG;                            // 2M f32
  float* I  = Wk + 12*MEG;                            // 8192x192
  float* J  = I + 1572864;                            // 8192x96
  float* Kw = J + 786432;                             // 65536x96
  unsigned short* vb = (unsigned short*)(Wk + 21*MEG); // values bf16
  unsigned short* Hb = (unsigned short*)(Wk + 34*MEG); // vproj bf16
  unsigned short* dG = (unsigned short*)(Wk + 47*MEG); // gather out bf16

  unsigned short* sa_inT  = WT;
  unsigned short* sa_outT = WT + 196608;
  unsigned short* sa_l1T  = WT + 262144;
  unsigned short* sa_l2T  = WT + 524288;
  unsigned short* da_valT = WT + 786432;
  unsigned short* da_outT = WT + 851968;
  unsigned short* ff1T    = WT + 917504;
  unsigned short* ff2T    = WT + 1179648;

  WPack wp_;
  wp_.e[0] = { sa_in_w, sa_inT, 256, 768 };
  wp_.e[1] = { sa_out_w, sa_outT, 256, 256 };
  wp_.e[2] = { sa_l1_w, sa_l1T, 256, 1024 };
  wp_.e[3] = { sa_l2_w, sa_l2T, 1024, 256 };
  wp_.e[4] = { da_val_w, da_valT, 256, 256 };
  wp_.e[5] = { da_out_w, da_outT, 256, 256 };
  wp_.e[6] = { ff1_w, ff1T, 256, 1024 };
  wp_.e[7] = { ff2_w, ff2T, 1024, 256 };

  dim3 blk(256);
  k_wtcvt<<<dim3(64,8), blk, 0, stream>>>(wp_);
  k_f2b8<<<13125, blk, 0, stream>>>((const float4*)values, (uint4*)vb);
  k_prep<<<2048, blk, 0, stream>>>((const float4*)qe,(const float4*)rf,
                                   (const float4*)qo,(const float4*)rp,
                                   (float4*)A,(uint2*)srcb,(uint2*)qb);
  k_gemm_bf<false><<<dim3(4,64), blk, 0, stream>>>(qb,256, sa_inT, sa_in_b, qk,nullptr,512, 8192,512,256, 0);
  k_gemm_bf<false><<<dim3(2,64), blk, 0, stream>>>(srcb,256, sa_inT+512*256, sa_in_b+512, vp,nullptr,256, 8192,256,256, 0);
  k_cvt<<<128, blk, 0, stream>>>(qk, vp, Kbf, Vtb);
  k_attn2<<<dim3(16,64), blk, 0, stream>>>(qk, Kbf, Vtb, qmask, aob);
  k_gemm_bf<false><<<dim3(2,64), blk, 0, stream>>>(aob,256, sa_outT, sa_out_b, F,nullptr,256, 8192,256,256, 0);
  k_addln<<<2048, blk, 0, stream>>>(A, F, sa_ln1_g, sa_ln1_b, A, (uint2*)Ab);
  k_gemm_bf<true><<<dim3(8,64), blk, 0, stream>>>(Ab,256, sa_l1T, sa_l1_b, nullptr,hidb,1024, 8192,1024,256, 1);
  k_gemm_bf<false><<<dim3(2,64), blk, 0, stream>>>(hidb,1024, sa_l2T, sa_l2_b, F,nullptr,256, 8192,256,1024, 0);
  k_addln<<<2048, blk, 0, stream>>>(A, F, sa_ln2_g, sa_ln2_b, A, (uint2*)Ab);
  k_dq<<<2048, blk, 0, stream>>>((const float4*)A,(const float4*)qo,
                                 (const float4*)rp,(const float4*)rf,(float4*)dq);
  k_gemm<<<dim3(3,128), blk, 0, stream>>>(dq,256, da_off_w,192, da_off_b, I,192, 8192,192,256, 0);
  k_gemm<<<dim3(2,128), blk, 0, stream>>>(dq,256, da_att_w,96, da_att_b, J,96, 8192,96,256, 0);
  k_gemm_bf<true><<<dim3(2,821), blk, 0, stream>>>(vb,256, da_valT, da_val_b, nullptr,Hb,256, 105000,256,256, 0);
  k_dwt<<<256, blk, 0, stream>>>(I, J, refp, Kw);
  k_dgather<<<8192, blk, 0, stream>>>(Hb, Kw, dG);
  k_gemm_bf<false><<<dim3(2,64), blk, 0, stream>>>(dG,256, da_outT, da_out_b, F,nullptr,256, 8192,256,256, 0);
  k_addln<<<2048, blk, 0, stream>>>(A, F, ln1_g, ln1_b, A, (uint2*)Ab);
  k_gemm_bf<true><<<dim3(8,64), blk, 0, stream>>>(Ab,256, ff1T, ff1_b, nullptr,hidb,1024, 8192,1024,256, 1);
  k_gemm_bf<false><<<dim3(2,64), blk, 0, stream>>>(hidb,1024, ff2T, ff2_b, F,nullptr,256, 8192,256,1024, 0);
  k_addln<<<2048, blk, 0, stream>>>(A, F, ln2_g, ln2_b, (float*)d_out, nullptr);
}